// Round 7
// baseline (216.486 us; speedup 1.0000x reference)
//
#include <hip/hip_runtime.h>

#define S_VOX (128*128*128)   // spatial voxels per (b,n) plane = 2097152
#define QV (S_VOX/4)          // float4 groups per plane = 524288
#define SEGS 256              // segments per plane
#define SEG_Q (QV / SEGS)     // 2048 q-groups per segment (8 iters x 256 thr)
#define EPSF 1e-10f
#define SMOOTHF 1e-5f

// ws: 8 replicas (one per XCD) of accumulators, stride 64 floats:
//   [0] ce_sum, [1+plane] inter, [17+plane] ground, [33+plane] pred_o
// codes buffer (2 MB, uchar/voxel: t0 | t1<<3) lives at ws + 4096 floats.
#define NREP 8
#define REP_STRIDE 64
#define CODES_OFF 4096

__device__ __forceinline__ float wave_reduce(float v) {
#pragma unroll
    for (int off = 32; off > 0; off >>= 1)
        v += __shfl_down(v, off, 64);
    return v;
}

// Pre-pass: pack both batches' targets into 1 byte/voxel. 25 MB traffic (~5us)
// paid once; main kernel's target stream shrinks 16x (33.6 -> 2 MB unique).
__global__ __launch_bounds__(256) void encode_tgt(const int* __restrict__ tgt,
                                                  unsigned char* __restrict__ codes) {
    const int idx = blockIdx.x * 256 + threadIdx.x;   // uchar4 group, QV total
    const int4 a = ((const int4*)tgt)[idx];            // batch 0
    const int4 b = ((const int4*)tgt)[QV + idx];       // batch 1
    uchar4 c;
    c.x = (unsigned char)(a.x | (b.x << 3));
    c.y = (unsigned char)(a.y | (b.y << 3));
    c.z = (unsigned char)(a.z | (b.z << 3));
    c.w = (unsigned char)(a.w | (b.w << 3));
    ((uchar4*)codes)[idx] = c;
}

// R7: fix the memory-queue DUTY CYCLE. R0-R6 all ran load->vmcnt(0)->long
// pure-VALU stretch with ZERO loads in flight (VALUBusy ~23% = queue-idle
// fraction); per-CU throughput = outstanding/latency was capped at ~2.4 TB/s
// while the harness's own fillBuffer hit 6.74 TB/s in the same capture.
// Here: 3 named register sets (static, rule#20-safe) rotate so 2 iterations'
// loads (6 loads) are ALWAYS outstanding while a third is consumed;
// sched_barrier(0) after each load bundle stops hipcc sinking loads back
// under the consume (it did exactly that in R4, VGPR 68). Compiler emits
// counted vmcnt(6) waits. Streams: 2 pred (planes (0,n),(1,n)) + uchar4 codes.
// CE fold: c_n = (t0==n)+(t1==n) is batch-independent ->
//   ce += c_n * log((p0+E)*(p1+E)).
__global__ __launch_bounds__(256) void dice_main(const float* __restrict__ pred,
                                                 const unsigned char* __restrict__ codes,
                                                 float* __restrict__ ws) {
    // id = xcd + 8*n + 64*seghi : the 8 n-sharers of a segment's codes have
    // ids spaced 8 apart (same XCD, 64-id dispatch window).
    const int xcd   = blockIdx.x & 7;
    const int r     = blockIdx.x >> 3;
    const int n     = r & 7;
    const int seg   = ((r >> 3) << 3) | xcd;          // 0..255

    const size_t base = (size_t)seg * SEG_Q;
    const float4* p0 = (const float4*)pred + (size_t)n       * QV + base; // b0,n
    const float4* p1 = (const float4*)pred + (size_t)(8 + n) * QV + base; // b1,n
    const uchar4* cd = (const uchar4*)codes + base;

    float ce = 0.f, in0 = 0.f, in1 = 0.f, po0 = 0.f, po1 = 0.f;
    int   g0 = 0, g1 = 0;

    const int i0 = threadIdx.x;

#define LD(q0_, q1_, c_, k)                                             \
    { q0_ = p0[i0 + (k) * 256]; q1_ = p1[i0 + (k) * 256]; c_ = cd[i0 + (k) * 256]; }

#define VOX(pa, pb, cc)                                                 \
    {                                                                   \
        const int m0 = (((cc) & 7) == n);                               \
        const int m1 = ((((cc) >> 3) & 7) == n);                        \
        in0 += m0 ? (pa) : 0.f;  g0 += m0;                              \
        in1 += m1 ? (pb) : 0.f;  g1 += m1;                              \
        ce  += (float)(m0 + m1) * __logf(((pa) + EPSF) * ((pb) + EPSF)); \
        po0 += (pa);  po1 += (pb);                                      \
    }
#define CONS(q0_, q1_, c_)                                              \
    {                                                                   \
        VOX(q0_.x, q1_.x, c_.x)                                         \
        VOX(q0_.y, q1_.y, c_.y)                                         \
        VOX(q0_.z, q1_.z, c_.z)                                         \
        VOX(q0_.w, q1_.w, c_.w)                                         \
    }
#define SB __builtin_amdgcn_sched_barrier(0)

    float4 a0, a1, b0, b1, c0, c1;
    uchar4 ac, bc, cc;
    LD(a0, a1, ac, 0)
    LD(b0, b1, bc, 1)
    SB;
    LD(c0, c1, cc, 2) SB; CONS(a0, a1, ac)
    LD(a0, a1, ac, 3) SB; CONS(b0, b1, bc)
    LD(b0, b1, bc, 4) SB; CONS(c0, c1, cc)
    LD(c0, c1, cc, 5) SB; CONS(a0, a1, ac)
    LD(a0, a1, ac, 6) SB; CONS(b0, b1, bc)
    LD(b0, b1, bc, 7) SB; CONS(c0, c1, cc)
    CONS(a0, a1, ac)
    CONS(b0, b1, bc)
#undef SB
#undef CONS
#undef VOX
#undef LD

    // ---- block reduction: 7 scalars ----
    __shared__ float red[4][7];
    const int lane = threadIdx.x & 63;
    const int wave = threadIdx.x >> 6;
    float acc[7] = { ce, in0, in1, (float)g0, (float)g1, po0, po1 };
#pragma unroll
    for (int k = 0; k < 7; k++) {
        float v = wave_reduce(acc[k]);
        if (lane == 0) red[wave][k] = v;
    }
    __syncthreads();
    if (threadIdx.x < 7) {
        const int k = threadIdx.x;
        const float s = red[0][k] + red[1][k] + red[2][k] + red[3][k];
        // plane (b=0,n)=n, (b=1,n)=8+n
        static const int off[7] = { 0, 1, 9, 17, 25, 33, 41 };
        // dst: ce->0; in0->1+n; in1->1+8+n; g0->17+n; g1->17+8+n; po0->33+n; po1->33+8+n
        const int dst = (k == 0) ? 0 : off[k] + n;
        atomicAdd(&ws[xcd * REP_STRIDE + dst], s);
    }
}

__global__ void dice_finalize(const float* __restrict__ ws, float* __restrict__ out) {
    const int i = threadIdx.x;
    float term = 0.f;
    if (i < 16) {
        float inter = 0.f, g = 0.f, p = 0.f;
#pragma unroll
        for (int rp = 0; rp < NREP; rp++) {
            inter += ws[rp * REP_STRIDE + 1  + i];
            g     += ws[rp * REP_STRIDE + 17 + i];
            p     += ws[rp * REP_STRIDE + 33 + i];
        }
        term = 1.0f - (2.0f * inter + SMOOTHF) / (g + p + SMOOTHF);
    }
    term = wave_reduce(term);
    if (i == 0) {
        float ce = 0.f;
#pragma unroll
        for (int rp = 0; rp < NREP; rp++) ce += ws[rp * REP_STRIDE];
        // celoss = -ce_sum / (B*B*S)  with B=2
        float celoss = -ce / (4.0f * (float)S_VOX);
        out[0] = celoss + term * (1.0f / 16.0f);
    }
}

extern "C" void kernel_launch(void* const* d_in, const int* in_sizes, int n_in,
                              void* d_out, int out_size, void* d_ws, size_t ws_size,
                              hipStream_t stream) {
    const float* pred = (const float*)d_in[0];
    const int*   tgt  = (const int*)d_in[1];
    float* ws  = (float*)d_ws;
    float* out = (float*)d_out;
    unsigned char* codes = (unsigned char*)(ws + CODES_OFF);

    hipMemsetAsync(ws, 0, NREP * REP_STRIDE * sizeof(float), stream);
    encode_tgt<<<QV / 256, 256, 0, stream>>>(tgt, codes);
    // 2048 blocks = 8 n-planes x 256 segments, XCD-grouped code sharing
    dice_main<<<8 * SEGS, 256, 0, stream>>>(pred, codes, ws);
    dice_finalize<<<1, 64, 0, stream>>>(ws, out);
}

// Round 10
// 197.928 us; speedup vs baseline: 1.0938x; 1.0938x over previous
//
#include <hip/hip_runtime.h>

#define S_VOX (128*128*128)   // spatial voxels per (b,n) plane = 2097152
#define QV (S_VOX/4)          // float4 groups per plane = 524288
#define SEG_Q 1024            // q-groups per segment (4 iters x 256 threads)
#define SEGS (QV / SEG_Q)     // 512 segments per plane
#define EPSF 1e-10f
#define SMOOTHF 1e-5f

// ws: 8 replicas (one per XCD) of accumulators, stride 64 floats:
//   [0] ce_sum, [1+plane] inter, [17+plane] ground, [33+plane] pred_o
// codes buffer (2 MB, uchar/voxel: t0 | t1<<3) lives at ws + 4096 floats.
#define NREP 8
#define REP_STRIDE 64
#define CODES_OFF 4096

// native clang vector type: __builtin_nontemporal_load requires scalar /
// pointer / native-vector element types (HIP_vector_type<float,4> is a class
// and was rejected by the round-9 compile).
typedef float vf4 __attribute__((ext_vector_type(4)));

__device__ __forceinline__ float wave_reduce(float v) {
#pragma unroll
    for (int off = 32; off > 0; off >>= 1)
        v += __shfl_down(v, off, 64);
    return v;
}

// Pre-pass: pack both batches' targets into 1 byte/voxel (t0 | t1<<3).
__global__ __launch_bounds__(256) void encode_tgt(const int* __restrict__ tgt,
                                                  unsigned char* __restrict__ codes) {
    const int idx = blockIdx.x * 256 + threadIdx.x;   // uchar4 group, QV total
    const int4 a = ((const int4*)tgt)[idx];            // batch 0
    const int4 b = ((const int4*)tgt)[QV + idx];       // batch 1
    uchar4 c;
    c.x = (unsigned char)(a.x | (b.x << 3));
    c.y = (unsigned char)(a.y | (b.y << 3));
    c.z = (unsigned char)(a.z | (b.z << 3));
    c.w = (unsigned char)(a.w | (b.w << 3));
    ((uchar4*)codes)[idx] = c;
}

// R10 = R8/R9 design, NT-load type fixed (ext_vector_type). Decisive
// read-path test: read-dominated variants cap at ~2.4 TB/s demand across 7
// structures while the harness's write-only fill hits 6.9 TB/s in the same
// capture, and Little's law shows in-flight bytes were already 5-8x
// sufficient -> suspect the cached-load return path, not concurrency.
// (1) pred streams use NONTEMPORAL loads (no cache allocation; pred has zero
//     intra-dispatch reuse) -> stream straight from HBM like the fill.
//     codes stay cached (8x reuse across n-planes on the same XCD).
// (2) all 12 loads (4 iters x 3 streams, ~9 KB/wave) issued up front behind
//     sched_barrier(0) (R7-proven fence that stops hipcc re-sinking loads
//     under the consume, which it did in R4), consumed in issue order ->
//     compiler emits counted vmcnt; ~64 VGPR keeps full occupancy.
// CE fold: c_n = (t0==n)+(t1==n) is batch-independent ->
//   ce += c_n * log((p0+E)*(p1+E)).
__global__ __launch_bounds__(256) void dice_main(const float* __restrict__ pred,
                                                 const unsigned char* __restrict__ codes,
                                                 float* __restrict__ ws) {
    // id = xcd + 8*n + 64*seghi : the 8 n-sharers of a segment's codes have
    // ids spaced 8 apart (same XCD, 64-id dispatch window).
    const int xcd   = blockIdx.x & 7;
    const int r     = blockIdx.x >> 3;
    const int n     = r & 7;
    const int seg   = ((r >> 3) << 3) | xcd;          // 0..511

    const size_t base = (size_t)seg * SEG_Q;
    const vf4*    p0 = (const vf4*)pred + (size_t)n       * QV + base; // b0,n
    const vf4*    p1 = (const vf4*)pred + (size_t)(8 + n) * QV + base; // b1,n
    const uchar4* cd = (const uchar4*)codes + base;

    float ce = 0.f, in0 = 0.f, in1 = 0.f, po0 = 0.f, po1 = 0.f;
    int   g0 = 0, g1 = 0;

    const int i0 = threadIdx.x;

    // ---- issue ALL loads up front: 12 vector loads, ~36 data VGPRs ----
    vf4 A[4], B[4];
    uchar4 C[4];
#pragma unroll
    for (int k = 0; k < 4; k++) {
        const int i = i0 + k * 256;
        A[k] = __builtin_nontemporal_load(&p0[i]);   // pred b0: NT stream
        B[k] = __builtin_nontemporal_load(&p1[i]);   // pred b1: NT stream
        C[k] = cd[i];                                // codes: cached (8x reuse)
    }
    __builtin_amdgcn_sched_barrier(0);   // fence: loads stay above the consume

#define VOX(pa, pb, cc)                                                  \
    {                                                                    \
        const int m0 = (((cc) & 7) == n);                                \
        const int m1 = ((((cc) >> 3) & 7) == n);                         \
        in0 += m0 ? (pa) : 0.f;  g0 += m0;                               \
        in1 += m1 ? (pb) : 0.f;  g1 += m1;                               \
        ce  += (float)(m0 + m1) * __logf(((pa) + EPSF) * ((pb) + EPSF)); \
        po0 += (pa);  po1 += (pb);                                       \
    }
#pragma unroll
    for (int k = 0; k < 4; k++) {
        VOX(A[k].x, B[k].x, C[k].x)
        VOX(A[k].y, B[k].y, C[k].y)
        VOX(A[k].z, B[k].z, C[k].z)
        VOX(A[k].w, B[k].w, C[k].w)
    }
#undef VOX

    // ---- block reduction: 7 scalars ----
    __shared__ float red[4][7];
    const int lane = threadIdx.x & 63;
    const int wave = threadIdx.x >> 6;
    float acc[7] = { ce, in0, in1, (float)g0, (float)g1, po0, po1 };
#pragma unroll
    for (int k = 0; k < 7; k++) {
        float v = wave_reduce(acc[k]);
        if (lane == 0) red[wave][k] = v;
    }
    __syncthreads();
    if (threadIdx.x < 7) {
        const int k = threadIdx.x;
        const float s = red[0][k] + red[1][k] + red[2][k] + red[3][k];
        // dst mapping (plane b0,n -> n; b1,n -> 8+n):
        //   k=0: ce -> 0
        //   k=1: in0 -> 1+n      k=2: in1 -> 1+8+n
        //   k=3: g0  -> 17+n     k=4: g1  -> 17+8+n
        //   k=5: po0 -> 33+n     k=6: po1 -> 33+8+n
        int dst;
        if (k == 0)      dst = 0;
        else if (k <= 2) dst = 1  + (k - 1) * 8 + n;
        else if (k <= 4) dst = 17 + (k - 3) * 8 + n;
        else             dst = 33 + (k - 5) * 8 + n;
        atomicAdd(&ws[xcd * REP_STRIDE + dst], s);
    }
}

__global__ void dice_finalize(const float* __restrict__ ws, float* __restrict__ out) {
    const int i = threadIdx.x;
    float term = 0.f;
    if (i < 16) {
        float inter = 0.f, g = 0.f, p = 0.f;
#pragma unroll
        for (int rp = 0; rp < NREP; rp++) {
            inter += ws[rp * REP_STRIDE + 1  + i];
            g     += ws[rp * REP_STRIDE + 17 + i];
            p     += ws[rp * REP_STRIDE + 33 + i];
        }
        term = 1.0f - (2.0f * inter + SMOOTHF) / (g + p + SMOOTHF);
    }
    term = wave_reduce(term);
    if (i == 0) {
        float ce = 0.f;
#pragma unroll
        for (int rp = 0; rp < NREP; rp++) ce += ws[rp * REP_STRIDE];
        // celoss = -ce_sum / (B*B*S)  with B=2
        float celoss = -ce / (4.0f * (float)S_VOX);
        out[0] = celoss + term * (1.0f / 16.0f);
    }
}

extern "C" void kernel_launch(void* const* d_in, const int* in_sizes, int n_in,
                              void* d_out, int out_size, void* d_ws, size_t ws_size,
                              hipStream_t stream) {
    const float* pred = (const float*)d_in[0];
    const int*   tgt  = (const int*)d_in[1];
    float* ws  = (float*)d_ws;
    float* out = (float*)d_out;
    unsigned char* codes = (unsigned char*)(ws + CODES_OFF);

    (void)hipMemsetAsync(ws, 0, NREP * REP_STRIDE * sizeof(float), stream);
    encode_tgt<<<QV / 256, 256, 0, stream>>>(tgt, codes);
    // 4096 blocks = 8 n-planes x 512 segments, XCD-grouped code sharing,
    // 4 one-shot iters/thread with all loads prefetched
    dice_main<<<8 * SEGS, 256, 0, stream>>>(pred, codes, ws);
    dice_finalize<<<1, 64, 0, stream>>>(ws, out);
}